// Round 16
// baseline (143.366 us; speedup 1.0000x reference)
//
#include <hip/hip_runtime.h>
#include <hip/hip_fp16.h>
#include <math.h>

#define N_ATOMS 10000
#define N_EDGES 320000
#define C 32
#define NB 8
#define NCOMB 11
#define ED_STRIDE 8    // floats per edge record (32 B)
#define CAP 80         // fixed record capacity per atom (mean deg 32)

// ---- tier0 ws layout (byte offsets) ----
#define T0_CURSOR   0u
#define T0_WT       40960u                    // 32*56 words = 7168 B
#define T0_EDATA    49152u                    // 10000*80*32 = 25,600,000 B
#define T0_XPACK    25649152u                 // 320000*32  = 10,240,000 B
#define T0_NEED     35889152u

// ---- fallback (R14 tier2) ws layout ----
#define WS_COUNTS   0u
#define WS_OFFSETS  40960u
#define WS_CURSOR   81920u
#define WS_WT       122880u
#define WS_EDATA    139264u
#define WS_TIER2    10379264u

typedef _Float16 h2_t __attribute__((ext_vector_type(2)));

__device__ __forceinline__ float2 h2f(unsigned int u) {
    union { unsigned int u; __half2 h; } cv; cv.u = u;
    return __half22float2(cv.h);
}
__device__ __forceinline__ unsigned int f2h(float x, float y) {
    union { unsigned int u; __half2 h; } cv;
    cv.h = __float22half2_rn(make_float2(x, y));
    return cv.u;
}
// f32 += dot(fp16x2, fp16x2) via the compiler-visible intrinsic (hazards handled)
__device__ __forceinline__ float FDOT2(unsigned int a, unsigned int b, float acc) {
    union { unsigned int u; h2_t h; } A, B; A.u = a; B.u = b;
    return __builtin_amdgcn_fdot2(A.h, B.h, acc, false);
}

// ============ TIER0: fused edge pass (hist-alloc + record + xpack + Wt) =====
// grid exactly N_EDGES/256 = 1250 blocks; N_EDGES == N_ATOMS*C.
__global__ __launch_bounds__(256) void fused_prep_kernel(
    const float* __restrict__ x0, const float* __restrict__ x1,
    const float* __restrict__ x2, const float* __restrict__ pos,
    const int* __restrict__ idx_i, const int* __restrict__ idx_j,
    const float* __restrict__ W, const float* __restrict__ b,
    int* __restrict__ cursor, unsigned int* __restrict__ Wt,
    float* __restrict__ edata, __half* __restrict__ xpack)
{
    int tid = threadIdx.x;
    int a0 = blockIdx.x * 256;
    int t = a0 + tid;

    // block 0: pack Wt (44 fp16x2 W nb-pairs + 11 f32 bias per channel)
    if (blockIdx.x == 0) {
        for (int idx = tid; idx < 32*56; idx += 256) {
            int c = idx / 56, s = idx % 56;
            unsigned int uv = 0;
            if (s < 44) {
                int k = s >> 2, p = s & 3;
                float wa = W[(k*NB + 2*p  )*C + c] * (1.0f/32.0f);
                float wb = W[(k*NB + 2*p+1)*C + c] * (1.0f/32.0f);
                uv = f2h(wa, wb);
            } else if (s < 55) {
                int k = s - 44;
                uv = __float_as_uint(b[k*C + c] * (1.0f/32.0f));
            }
            Wt[c*56 + s] = uv;
        }
    }

    // xpack build (t = (atom,channel) record id), LDS-staged coalesced reads
    __shared__ float sx1[768];
    __shared__ float sx2[2304];
    #pragma unroll
    for (int k = 0; k < 3; ++k) sx1[k*256 + tid] = x1[(size_t)a0*3 + k*256 + tid];
    #pragma unroll
    for (int k = 0; k < 9; ++k) sx2[k*256 + tid] = x2[(size_t)a0*9 + k*256 + tid];
    __syncthreads();

    {
        float v0  = x0[t];
        float v1x = sx1[tid*3+0], v1y = sx1[tid*3+1], v1z = sx1[tid*3+2];
        float b0 = sx2[tid*9+0], b1 = sx2[tid*9+1], b2 = sx2[tid*9+2];
        float b3 = sx2[tid*9+3], b4 = sx2[tid*9+4], b5 = sx2[tid*9+5];
        float b6 = sx2[tid*9+6], b7 = sx2[tid*9+7], b8 = sx2[tid*9+8];
        uint4* dst = (uint4*)(xpack + (size_t)t * 16);
        dst[0] = make_uint4(f2h(v0, v1x), f2h(v1y, v1z), f2h(b0, b1), f2h(b2, b3));
        dst[1] = make_uint4(f2h(b4, b5), f2h(b6, b7), f2h(b8, 0.0f), 0u);
    }

    // edge prep (t = edge id): geometry + rbf + slot-alloc + record write
    int i = idx_i[t], j = idx_j[t];
    float rx = pos[3*j+0] - pos[3*i+0];
    float ry = pos[3*j+1] - pos[3*i+1];
    float rz = pos[3*j+2] - pos[3*i+2];
    float d  = sqrtf(rx*rx + ry*ry + rz*rz + 1e-12f);
    float invd = 1.0f / d;
    float ux = rx*invd, uy = ry*invd, uz = rz*invd;

    const float PI = 3.14159265358979323846f;
    const float RC = 5.0f;
    float fc    = 0.5f * (cosf(PI * fminf(d, RC) / RC) + 1.0f);
    float pref  = sqrtf(2.0f / RC) * invd * fc;
    float phase = PI * d / RC;

    float s1, c1;
    sincosf(phase, &s1, &c1);
    float twoc = 2.0f * c1;
    float rbf[NB];
    float sp = 0.0f, sc = s1;
    #pragma unroll
    for (int nb = 0; nb < NB; ++nb) {
        rbf[nb] = pref * sc;
        float sn = twoc * sc - sp;
        sp = sc; sc = sn;
    }

    int slot = atomicAdd(&cursor[i], 1);
    float* rec = edata + ((size_t)i * CAP + slot) * ED_STRIDE;
    *(float4*)rec = make_float4(ux, uy, uz, __int_as_float(j));
    *((uint4*)rec + 1) = make_uint4(f2h(rbf[0], rbf[1]), f2h(rbf[2], rbf[3]),
                                    f2h(rbf[4], rbf[5]), f2h(rbf[6], rbf[7]));
}

// ============ TIER0 gather: wave/atom, fdot2 MLP, 4-stage pipeline ==========
// Stages: A = compute (rec+xpack resident); B = rec+xpack resident;
//         C = rec resident, xpack issued this iter; D = rec issued this iter.
__global__ __launch_bounds__(256) void gather_t0_kernel(
    const unsigned int* __restrict__ Wt, const int* __restrict__ cursor,
    const float* __restrict__ edata, const __half* __restrict__ xpack,
    float* __restrict__ out)
{
    int wave = (blockIdx.x * blockDim.x + threadIdx.x) >> 6;
    int lane = threadIdx.x & 63;
    int c = lane & 31;
    int h = lane >> 5;
    if (wave >= N_ATOMS) return;
    int a = wave;

    // pinned per-channel weights: 44 fp16x2 + 11 f32 bias = 55 VGPRs
    const unsigned int* wrow = Wt + c*56;
    unsigned int Wh[NCOMB][4];
    float bc[NCOMB];
    #pragma unroll
    for (int k = 0; k < NCOMB; ++k) {
        #pragma unroll
        for (int p = 0; p < 4; ++p) Wh[k][p] = wrow[k*4 + p];
        bc[k] = __uint_as_float(wrow[44 + k]);
    }
    #pragma unroll
    for (int k = 0; k < NCOMB; ++k) {
        asm volatile("" : "+v"(bc[k]));
        #pragma unroll
        for (int p = 0; p < 4; ++p) asm volatile("" : "+v"(Wh[k][p]));
    }

    float acc[13];
    #pragma unroll
    for (int q = 0; q < 13; ++q) acc[q] = 0.0f;

    int start = a * CAP;
    int end = start + cursor[a];

    int p = start + h;
    if (p < end) {
        // ---- pipeline prologue ----
        const float* rA = edata + (size_t)p * ED_STRIDE;
        float4 gA0 = *(const float4*)rA;
        uint4  gA1 = *((const uint4*)rA + 1);

        int pB = p + 2;
        bool hasB = pB < end;
        float4 gB0 = make_float4(0.f,0.f,0.f,0.f);
        uint4  gB1 = make_uint4(0u,0u,0u,0u);
        if (hasB) {
            const float* rB = edata + (size_t)pB * ED_STRIDE;
            gB0 = *(const float4*)rB;
            gB1 = *((const uint4*)rB + 1);
        }

        int pC = p + 4;
        bool hasC = pC < end;
        float4 gC0 = make_float4(0.f,0.f,0.f,0.f);
        uint4  gC1 = make_uint4(0u,0u,0u,0u);
        if (hasC) {
            const float* rC = edata + (size_t)pC * ED_STRIDE;
            gC0 = *(const float4*)rC;
            gC1 = *((const uint4*)rC + 1);
        }

        int jA = __float_as_int(gA0.w);
        const uint4* xbA = (const uint4*)(xpack + ((size_t)(jA*C + c) << 4));
        uint4 loA = xbA[0], hiA = xbA[1];
        uint4 loB = make_uint4(0u,0u,0u,0u), hiB = make_uint4(0u,0u,0u,0u);
        if (hasB) {
            int jB = __float_as_int(gB0.w);
            const uint4* xbB = (const uint4*)(xpack + ((size_t)(jB*C + c) << 4));
            loB = xbB[0];
            hiB = xbB[1];
        }

        int pD = p + 6;

        while (1) {
            // issue stage-D record load (3 ahead)
            bool hasD = pD < end;
            float4 gD0 = make_float4(0.f,0.f,0.f,0.f);
            uint4  gD1 = make_uint4(0u,0u,0u,0u);
            if (hasD) {
                const float* rD = edata + (size_t)pD * ED_STRIDE;
                gD0 = *(const float4*)rD;
                gD1 = *((const uint4*)rD + 1);
            }
            // issue stage-C xpack load (2-body cover before use)
            uint4 loC = make_uint4(0u,0u,0u,0u), hiC = make_uint4(0u,0u,0u,0u);
            if (hasC) {
                int jC = __float_as_int(gC0.w);
                const uint4* xbC = (const uint4*)(xpack + ((size_t)(jC*C + c) << 4));
                loC = xbC[0];
                hiC = xbC[1];
            }

            // ---- compute body on stage A ----
            float fn[NCOMB];
            #pragma unroll
            for (int k = 0; k < NCOMB; ++k)
                fn[k] = FDOT2(gA1.w, Wh[k][3],
                        FDOT2(gA1.z, Wh[k][2],
                        FDOT2(gA1.y, Wh[k][1],
                        FDOT2(gA1.x, Wh[k][0], bc[k]))));

            float2 X0 = h2f(loA.x), X1 = h2f(loA.y), X2 = h2f(loA.z);
            float2 X3 = h2f(loA.w), X4 = h2f(hiA.x), X5 = h2f(hiA.y), X6 = h2f(hiA.z);
            float ux = gA0.x, uy = gA0.y, uz = gA0.z;
            float v0 = X0.x, v1x = X0.y, v1y = X1.x, v1z = X1.y;
            float c0 = X2.x, c1v = X2.y, c2 = X3.x, c3 = X3.y;
            float c4 = X4.x, c5 = X4.y, c6 = X5.x, c7 = X5.y, c8 = X6.x;

            float t2x = c0*ux + c1v*uy + c2*uz;
            float t2y = c3*ux + c4*uy + c5*uz;
            float t2z = c6*ux + c7*uy + c8*uz;
            float s1 = v1x*ux + v1y*uy + v1z*uz;
            float s2 = t2x*ux + t2y*uy + t2z*uz;

            acc[0] += fn[0]*v0 + fn[4]*s1 + fn[9]*s2;
            float al = fn[1]*v0 + fn[6]*s1;
            acc[1] += al*ux + fn[3]*v1x + fn[8]*t2x;
            acc[2] += al*uy + fn[3]*v1y + fn[8]*t2y;
            acc[3] += al*uz + fn[3]*v1z + fn[8]*t2z;
            float be = fn[2]*v0;
            float cax = be*ux + fn[5]*v1x + fn[10]*t2x;
            float cay = be*uy + fn[5]*v1y + fn[10]*t2y;
            float caz = be*uz + fn[5]*v1z + fn[10]*t2z;
            acc[4]  += cax*ux + fn[7]*c0;
            acc[5]  += cax*uy + fn[7]*c1v;
            acc[6]  += cax*uz + fn[7]*c2;
            acc[7]  += cay*ux + fn[7]*c3;
            acc[8]  += cay*uy + fn[7]*c4;
            acc[9]  += cay*uz + fn[7]*c5;
            acc[10] += caz*ux + fn[7]*c6;
            acc[11] += caz*uy + fn[7]*c7;
            acc[12] += caz*uz + fn[7]*c8;

            if (!hasB) break;
            // rotate pipeline: A<-B, B<-C (xpack from this iter's issue), C<-D
            gA0 = gB0; gA1 = gB1; loA = loB; hiA = hiB;
            gB0 = gC0; gB1 = gC1; loB = loC; hiB = hiC;
            gC0 = gD0; gC1 = gD1;
            hasB = hasC; hasC = hasD;
            pD += 2;
        }
    }

    #pragma unroll
    for (int q = 0; q < 13; ++q)
        acc[q] += __shfl_xor(acc[q], 32);

    if (h == 0) {
        float* out0 = out;
        float* out1 = out + N_ATOMS * C;
        float* out2 = out + N_ATOMS * C * 4;
        out0[a*C + c] = acc[0];
        #pragma unroll
        for (int m = 0; m < 3; ++m) out1[(a*C + c)*3 + m] = acc[1+m];
        #pragma unroll
        for (int q = 0; q < 9; ++q) out2[(a*C + c)*9 + q] = acc[4+q];
    }
}

// ============ FALLBACK tier2 (scan-based CSR, original x layouts) ===========
__global__ __launch_bounds__(256) void aux_kernel(
    const int* __restrict__ idx_i, int* __restrict__ counts)
{
    int t = blockIdx.x * blockDim.x + threadIdx.x;
    if (t < N_EDGES) atomicAdd(&counts[idx_i[t]], 1);
}

__global__ __launch_bounds__(1024) void scan_kernel(
    const int* __restrict__ counts, int* __restrict__ offsets,
    int* __restrict__ cursor)
{
    __shared__ int part[1024];
    const int PER = 10;
    int t = threadIdx.x;
    int base = t * PER;
    int s = 0;
    #pragma unroll
    for (int k = 0; k < PER; ++k) {
        int idx = base + k;
        s += (idx < N_ATOMS) ? counts[idx] : 0;
    }
    part[t] = s;
    __syncthreads();
    for (int off = 1; off < 1024; off <<= 1) {
        int v = (t >= off) ? part[t - off] : 0;
        __syncthreads();
        part[t] += v;
        __syncthreads();
    }
    int run = (t == 0) ? 0 : part[t - 1];
    #pragma unroll
    for (int k = 0; k < PER; ++k) {
        int idx = base + k;
        if (idx < N_ATOMS) { offsets[idx] = run; cursor[idx] = run; run += counts[idx]; }
    }
    if (t == 1023) offsets[N_ATOMS] = part[1023];
}

__global__ __launch_bounds__(256) void prep_scatter_kernel(
    const float* __restrict__ pos, const int* __restrict__ idx_i,
    const int* __restrict__ idx_j, int* __restrict__ cursor,
    float* __restrict__ edata)
{
    int e = blockIdx.x * blockDim.x + threadIdx.x;
    if (e >= N_EDGES) return;
    int i = idx_i[e], j = idx_j[e];
    float rx = pos[3*j+0] - pos[3*i+0];
    float ry = pos[3*j+1] - pos[3*i+1];
    float rz = pos[3*j+2] - pos[3*i+2];
    float d  = sqrtf(rx*rx + ry*ry + rz*rz + 1e-12f);
    float invd = 1.0f / d;
    float ux = rx*invd, uy = ry*invd, uz = rz*invd;
    const float PI = 3.14159265358979323846f;
    const float RC = 5.0f;
    float fc    = 0.5f * (cosf(PI * fminf(d, RC) / RC) + 1.0f);
    float pref  = sqrtf(2.0f / RC) * invd * fc;
    float phase = PI * d / RC;
    float s1, c1;
    sincosf(phase, &s1, &c1);
    float twoc = 2.0f * c1;
    float rbf[NB];
    float sp = 0.0f, sc = s1;
    #pragma unroll
    for (int nb = 0; nb < NB; ++nb) {
        rbf[nb] = pref * sc;
        float sn = twoc * sc - sp;
        sp = sc; sc = sn;
    }
    int slot = atomicAdd(&cursor[i], 1);
    float* rec = edata + (size_t)slot * ED_STRIDE;
    *(float4*)rec = make_float4(ux, uy, uz, __int_as_float(j));
    *((uint4*)rec + 1) = make_uint4(f2h(rbf[0], rbf[1]), f2h(rbf[2], rbf[3]),
                                    f2h(rbf[4], rbf[5]), f2h(rbf[6], rbf[7]));
}

__global__ __launch_bounds__(256, 2) void gather_fallback(
    const float* __restrict__ x0, const float* __restrict__ x1,
    const float* __restrict__ x2, const float* __restrict__ W,
    const float* __restrict__ b, const int* __restrict__ offsets,
    const float* __restrict__ edata, float* __restrict__ out)
{
    int wave = (blockIdx.x * blockDim.x + threadIdx.x) >> 6;
    int lane = threadIdx.x & 63;
    int c = lane & 31;
    int h = lane >> 5;
    if (wave >= N_ATOMS) return;
    int a = wave;

    float Wc[NCOMB][NB], bc[NCOMB];
    #pragma unroll
    for (int k = 0; k < NCOMB; ++k) {
        bc[k] = b[k*C + c] * (1.0f / 32.0f);
        #pragma unroll
        for (int nb = 0; nb < NB; ++nb)
            Wc[k][nb] = W[(k*NB + nb)*C + c] * (1.0f / 32.0f);
    }
    #pragma unroll
    for (int k = 0; k < NCOMB; ++k) {
        asm volatile("" : "+v"(bc[k]));
        #pragma unroll
        for (int nb = 0; nb < NB; ++nb) asm volatile("" : "+v"(Wc[k][nb]));
    }

    float acc[13];
    #pragma unroll
    for (int q = 0; q < 13; ++q) acc[q] = 0.0f;

    int start = offsets[a], end = offsets[a + 1];
    for (int p = start + h; p < end; p += 2) {
        const float* rec = edata + (size_t)p * ED_STRIDE;
        float4 g0 = *(const float4*)rec;
        uint4  g1 = *((const uint4*)rec + 1);
        float2 rp0 = h2f(g1.x), rp1 = h2f(g1.y), rp2 = h2f(g1.z), rp3 = h2f(g1.w);
        float ux = g0.x, uy = g0.y, uz = g0.z;
        float rbf[NB] = {rp0.x, rp0.y, rp1.x, rp1.y, rp2.x, rp2.y, rp3.x, rp3.y};
        int j = __float_as_int(g0.w);
        float fn[NCOMB];
        #pragma unroll
        for (int k = 0; k < NCOMB; ++k) {
            float t = bc[k];
            #pragma unroll
            for (int nb = 0; nb < NB; ++nb) t = fmaf(rbf[nb], Wc[k][nb], t);
            fn[k] = t;
        }
        float v0 = x0[j*C + c];
        float v1[3], v2[9];
        #pragma unroll
        for (int m = 0; m < 3; ++m) v1[m] = x1[(j*C + c)*3 + m];
        #pragma unroll
        for (int m = 0; m < 9; ++m) v2[m] = x2[(j*C + c)*9 + m];
        float u[3] = {ux, uy, uz};
        float t2[3];
        #pragma unroll
        for (int q = 0; q < 3; ++q)
            t2[q] = v2[q*3+0]*ux + v2[q*3+1]*uy + v2[q*3+2]*uz;
        float s1 = v1[0]*ux + v1[1]*uy + v1[2]*uz;
        float s2 = t2[0]*ux + t2[1]*uy + t2[2]*uz;
        acc[0] += fn[0]*v0 + fn[4]*s1 + fn[9]*s2;
        #pragma unroll
        for (int m = 0; m < 3; ++m)
            acc[1+m] += fn[1]*v0*u[m] + fn[3]*v1[m] + fn[6]*s1*u[m] + fn[8]*t2[m];
        #pragma unroll
        for (int q = 0; q < 3; ++q) {
            float ca = fn[2]*v0*u[q] + fn[5]*v1[q] + fn[10]*t2[q];
            #pragma unroll
            for (int bb = 0; bb < 3; ++bb)
                acc[4 + q*3 + bb] += ca*u[bb] + fn[7]*v2[q*3 + bb];
        }
    }

    #pragma unroll
    for (int q = 0; q < 13; ++q)
        acc[q] += __shfl_xor(acc[q], 32);

    if (h == 0) {
        float* out0 = out;
        float* out1 = out + N_ATOMS * C;
        float* out2 = out + N_ATOMS * C * 4;
        out0[a*C + c] = acc[0];
        #pragma unroll
        for (int m = 0; m < 3; ++m) out1[(a*C + c)*3 + m] = acc[1+m];
        #pragma unroll
        for (int q = 0; q < 9; ++q) out2[(a*C + c)*9 + q] = acc[4+q];
    }
}

__global__ __launch_bounds__(256) void edge_atomic_kernel(
    const float* __restrict__ x0, const float* __restrict__ x1,
    const float* __restrict__ x2, const float* __restrict__ pos,
    const float* __restrict__ W, const float* __restrict__ b,
    const int* __restrict__ idx_i, const int* __restrict__ idx_j,
    float* __restrict__ out)
{
    int tid = blockIdx.x * blockDim.x + threadIdx.x;
    int e = tid >> 5;
    int c = tid & 31;
    if (e >= N_EDGES) return;
    int i = idx_i[e], j = idx_j[e];
    float rx = pos[3*j+0] - pos[3*i+0];
    float ry = pos[3*j+1] - pos[3*i+1];
    float rz = pos[3*j+2] - pos[3*i+2];
    float d  = sqrtf(rx*rx + ry*ry + rz*rz + 1e-12f);
    float invd = 1.0f / d;
    float ux = rx*invd, uy = ry*invd, uz = rz*invd;
    const float PI = 3.14159265358979323846f;
    const float RC = 5.0f;
    float fc   = 0.5f * (cosf(PI * fminf(d, RC) / RC) + 1.0f);
    float pref = sqrtf(2.0f / RC) * invd * fc;
    float phase = PI * d / RC;
    float rbf[NB];
    #pragma unroll
    for (int nb = 0; nb < NB; ++nb) rbf[nb] = pref * sinf((float)(nb+1) * phase);
    float fn[NCOMB];
    #pragma unroll
    for (int k = 0; k < NCOMB; ++k) {
        float acc = b[k*C + c];
        #pragma unroll
        for (int nb = 0; nb < NB; ++nb) acc += rbf[nb] * W[(k*NB + nb)*C + c];
        fn[k] = acc * (1.0f / 32.0f);
    }
    float v0 = x0[j*C + c];
    float v1[3], v2[9];
    #pragma unroll
    for (int m = 0; m < 3; ++m) v1[m] = x1[(j*C + c)*3 + m];
    #pragma unroll
    for (int m = 0; m < 9; ++m) v2[m] = x2[(j*C + c)*9 + m];
    float u[3] = {ux, uy, uz};
    float t2[3];
    #pragma unroll
    for (int q = 0; q < 3; ++q)
        t2[q] = v2[q*3+0]*ux + v2[q*3+1]*uy + v2[q*3+2]*uz;
    float s1 = v1[0]*ux + v1[1]*uy + v1[2]*uz;
    float s2 = t2[0]*ux + t2[1]*uy + t2[2]*uz;
    float* out0 = out;
    float* out1 = out + N_ATOMS * C;
    float* out2 = out + N_ATOMS * C * 4;
    atomicAdd(&out0[i*C + c], fn[0]*v0 + fn[4]*s1 + fn[9]*s2);
    #pragma unroll
    for (int m = 0; m < 3; ++m)
        atomicAdd(&out1[(i*C + c)*3 + m],
                  fn[1]*v0*u[m] + fn[3]*v1[m] + fn[6]*s1*u[m] + fn[8]*t2[m]);
    #pragma unroll
    for (int q = 0; q < 3; ++q) {
        float ca = fn[2]*v0*u[q] + fn[5]*v1[q] + fn[10]*t2[q];
        #pragma unroll
        for (int bb = 0; bb < 3; ++bb)
            atomicAdd(&out2[(i*C + c)*9 + q*3 + bb], ca*u[bb] + fn[7]*v2[q*3 + bb]);
    }
}

extern "C" void kernel_launch(void* const* d_in, const int* in_sizes, int n_in,
                              void* d_out, int out_size, void* d_ws, size_t ws_size,
                              hipStream_t stream) {
    const float* x0    = (const float*)d_in[0];
    const float* x1    = (const float*)d_in[1];
    const float* x2    = (const float*)d_in[2];
    const float* pos   = (const float*)d_in[3];
    const float* W     = (const float*)d_in[4];
    const float* b     = (const float*)d_in[5];
    const int*   idx_i = (const int*)d_in[6];
    const int*   idx_j = (const int*)d_in[7];
    float* out = (float*)d_out;

    int eb = 256, eg = (N_EDGES + eb - 1) / eb;   // 1250, exact
    int ggrid = (N_ATOMS + 3) / 4;

    if (ws_size >= T0_NEED) {
        char* ws = (char*)d_ws;
        int*          cursor = (int*)(ws + T0_CURSOR);
        unsigned int* Wt     = (unsigned int*)(ws + T0_WT);
        float*        edata  = (float*)(ws + T0_EDATA);
        __half*       xpack  = (__half*)(ws + T0_XPACK);

        hipMemsetAsync(cursor, 0, N_ATOMS * sizeof(int), stream);
        fused_prep_kernel<<<eg, eb, 0, stream>>>(x0, x1, x2, pos, idx_i, idx_j,
                                                 W, b, cursor, Wt, edata, xpack);
        gather_t0_kernel<<<ggrid, 256, 0, stream>>>(Wt, cursor, edata, xpack, out);
    } else if (ws_size >= WS_TIER2) {
        char* ws = (char*)d_ws;
        int*   counts  = (int*)(ws + WS_COUNTS);
        int*   offsets = (int*)(ws + WS_OFFSETS);
        int*   cursor  = (int*)(ws + WS_CURSOR);
        float* edata   = (float*)(ws + WS_EDATA);

        hipMemsetAsync(counts, 0, N_ATOMS * sizeof(int), stream);
        aux_kernel<<<eg, eb, 0, stream>>>(idx_i, counts);
        scan_kernel<<<1, 1024, 0, stream>>>(counts, offsets, cursor);
        prep_scatter_kernel<<<eg, eb, 0, stream>>>(pos, idx_i, idx_j, cursor, edata);
        gather_fallback<<<ggrid, 256, 0, stream>>>(x0, x1, x2, W, b,
                                                   offsets, edata, out);
    } else {
        hipMemsetAsync(d_out, 0, (size_t)out_size * sizeof(float), stream);
        int total_threads = N_EDGES * 32;
        int grid = (total_threads + 255) / 256;
        edge_atomic_kernel<<<grid, 256, 0, stream>>>(
            x0, x1, x2, pos, W, b, idx_i, idx_j, out);
    }
}

// Round 18
// 110.344 us; speedup vs baseline: 1.2993x; 1.2993x over previous
//
#include <hip/hip_runtime.h>
#include <hip/hip_fp16.h>
#include <math.h>

#define N_ATOMS 10000
#define N_EDGES 320000
#define C 32
#define NB 8
#define NCOMB 11
#define ED_STRIDE 8    // floats per edge record (32 B)
#define CAP 80         // fixed record capacity per atom (mean deg 32)

// ---- tier0 ws layout (byte offsets) ----
#define T0_CURSOR   0u
#define T0_WT       40960u                    // 32*56 words = 7168 B
#define T0_EDATA    49152u                    // 10000*80*32 = 25,600,000 B
#define T0_XPACK    25649152u                 // 320000*32  = 10,240,000 B
#define T0_NEED     35889152u

// ---- fallback (scan-based tier2) ws layout ----
#define WS_COUNTS   0u
#define WS_OFFSETS  40960u
#define WS_CURSOR   81920u
#define WS_WT       122880u
#define WS_EDATA    139264u
#define WS_TIER2    10379264u

typedef _Float16 h2_t __attribute__((ext_vector_type(2)));
typedef float        f32x4 __attribute__((ext_vector_type(4)));
typedef unsigned int u32x4 __attribute__((ext_vector_type(4)));

__device__ __forceinline__ float2 h2f(unsigned int u) {
    union { unsigned int u; __half2 h; } cv; cv.u = u;
    return __half22float2(cv.h);
}
__device__ __forceinline__ unsigned int f2h(float x, float y) {
    union { unsigned int u; __half2 h; } cv;
    cv.h = __float22half2_rn(make_float2(x, y));
    return cv.u;
}
// f32 += dot(fp16x2, fp16x2) via the compiler-visible intrinsic (hazards handled)
__device__ __forceinline__ float FDOT2(unsigned int a, unsigned int b, float acc) {
    union { unsigned int u; h2_t h; } A, B; A.u = a; B.u = b;
    return __builtin_amdgcn_fdot2(A.h, B.h, acc, false);
}

// ============ TIER0: fused edge pass (hist-alloc + record + xpack + Wt) =====
// grid exactly N_EDGES/256 = 1250 blocks; N_EDGES == N_ATOMS*C.
__global__ __launch_bounds__(256) void fused_prep_kernel(
    const float* __restrict__ x0, const float* __restrict__ x1,
    const float* __restrict__ x2, const float* __restrict__ pos,
    const int* __restrict__ idx_i, const int* __restrict__ idx_j,
    const float* __restrict__ W, const float* __restrict__ b,
    int* __restrict__ cursor, unsigned int* __restrict__ Wt,
    float* __restrict__ edata, __half* __restrict__ xpack)
{
    int tid = threadIdx.x;
    int a0 = blockIdx.x * 256;
    int t = a0 + tid;

    // block 0: pack Wt (44 fp16x2 W nb-pairs + 11 f32 bias per channel)
    if (blockIdx.x == 0) {
        for (int idx = tid; idx < 32*56; idx += 256) {
            int c = idx / 56, s = idx % 56;
            unsigned int uv = 0;
            if (s < 44) {
                int k = s >> 2, p = s & 3;
                float wa = W[(k*NB + 2*p  )*C + c] * (1.0f/32.0f);
                float wb = W[(k*NB + 2*p+1)*C + c] * (1.0f/32.0f);
                uv = f2h(wa, wb);
            } else if (s < 55) {
                int k = s - 44;
                uv = __float_as_uint(b[k*C + c] * (1.0f/32.0f));
            }
            Wt[c*56 + s] = uv;
        }
    }

    // xpack build (t = (atom,channel) record id), LDS-staged coalesced reads
    __shared__ float sx1[768];
    __shared__ float sx2[2304];
    #pragma unroll
    for (int k = 0; k < 3; ++k) sx1[k*256 + tid] = x1[(size_t)a0*3 + k*256 + tid];
    #pragma unroll
    for (int k = 0; k < 9; ++k) sx2[k*256 + tid] = x2[(size_t)a0*9 + k*256 + tid];
    __syncthreads();

    {
        float v0  = x0[t];
        float v1x = sx1[tid*3+0], v1y = sx1[tid*3+1], v1z = sx1[tid*3+2];
        float b0 = sx2[tid*9+0], b1 = sx2[tid*9+1], b2 = sx2[tid*9+2];
        float b3 = sx2[tid*9+3], b4 = sx2[tid*9+4], b5 = sx2[tid*9+5];
        float b6 = sx2[tid*9+6], b7 = sx2[tid*9+7], b8 = sx2[tid*9+8];
        uint4* dst = (uint4*)(xpack + (size_t)t * 16);
        dst[0] = make_uint4(f2h(v0, v1x), f2h(v1y, v1z), f2h(b0, b1), f2h(b2, b3));
        dst[1] = make_uint4(f2h(b4, b5), f2h(b6, b7), f2h(b8, 0.0f), 0u);
    }

    // edge prep (t = edge id): geometry + rbf + slot-alloc + record write
    int i = idx_i[t], j = idx_j[t];
    float rx = pos[3*j+0] - pos[3*i+0];
    float ry = pos[3*j+1] - pos[3*i+1];
    float rz = pos[3*j+2] - pos[3*i+2];
    float d  = sqrtf(rx*rx + ry*ry + rz*rz + 1e-12f);
    float invd = 1.0f / d;
    float ux = rx*invd, uy = ry*invd, uz = rz*invd;

    const float PI = 3.14159265358979323846f;
    const float RC = 5.0f;
    float fc    = 0.5f * (cosf(PI * fminf(d, RC) / RC) + 1.0f);
    float pref  = sqrtf(2.0f / RC) * invd * fc;
    float phase = PI * d / RC;

    float s1, c1;
    sincosf(phase, &s1, &c1);
    float twoc = 2.0f * c1;
    float rbf[NB];
    float sp = 0.0f, sc = s1;
    #pragma unroll
    for (int nb = 0; nb < NB; ++nb) {
        rbf[nb] = pref * sc;
        float sn = twoc * sc - sp;
        sp = sc; sc = sn;
    }

    int slot = atomicAdd(&cursor[i], 1);
    float* rec = edata + ((size_t)i * CAP + slot) * ED_STRIDE;
    // nontemporal: edata is streamed once by the gather; keep it out of L2
    f32x4 g0; g0.x = ux; g0.y = uy; g0.z = uz; g0.w = __int_as_float(j);
    u32x4 g1; g1.x = f2h(rbf[0], rbf[1]); g1.y = f2h(rbf[2], rbf[3]);
              g1.z = f2h(rbf[4], rbf[5]); g1.w = f2h(rbf[6], rbf[7]);
    __builtin_nontemporal_store(g0, (f32x4*)rec);
    __builtin_nontemporal_store(g1, (u32x4*)rec + 1);
}

// ============ TIER0 gather: wave/atom, fdot2 MLP, 3-stage pipeline ==========
__global__ __launch_bounds__(256) void gather_t0_kernel(
    const unsigned int* __restrict__ Wt, const int* __restrict__ cursor,
    const float* __restrict__ edata, const __half* __restrict__ xpack,
    float* __restrict__ out)
{
    int wave = (blockIdx.x * blockDim.x + threadIdx.x) >> 6;
    int lane = threadIdx.x & 63;
    int c = lane & 31;
    int h = lane >> 5;
    if (wave >= N_ATOMS) return;
    int a = wave;

    // pinned per-channel weights: 44 fp16x2 + 11 f32 bias = 55 VGPRs
    const unsigned int* wrow = Wt + c*56;
    unsigned int Wh[NCOMB][4];
    float bc[NCOMB];
    #pragma unroll
    for (int k = 0; k < NCOMB; ++k) {
        #pragma unroll
        for (int p = 0; p < 4; ++p) Wh[k][p] = wrow[k*4 + p];
        bc[k] = __uint_as_float(wrow[44 + k]);
    }
    #pragma unroll
    for (int k = 0; k < NCOMB; ++k) {
        asm volatile("" : "+v"(bc[k]));
        #pragma unroll
        for (int p = 0; p < 4; ++p) asm volatile("" : "+v"(Wh[k][p]));
    }

    float acc[13];
    #pragma unroll
    for (int q = 0; q < 13; ++q) acc[q] = 0.0f;

    int start = a * CAP;
    int end = start + cursor[a];

    int p = start + h;
    if (p < end) {
        // ---- pipeline prologue ----
        const float* rA = edata + (size_t)p * ED_STRIDE;
        f32x4 gA0 = __builtin_nontemporal_load((const f32x4*)rA);
        u32x4 gA1 = __builtin_nontemporal_load((const u32x4*)rA + 1);
        int pB = p + 2;
        bool hasB = pB < end;
        f32x4 gB0 = (f32x4)0.0f;
        u32x4 gB1 = (u32x4)0u;
        if (hasB) {
            const float* rB = edata + (size_t)pB * ED_STRIDE;
            gB0 = __builtin_nontemporal_load((const f32x4*)rB);
            gB1 = __builtin_nontemporal_load((const u32x4*)rB + 1);
        }
        int jA = __float_as_int(gA0.w);
        const uint4* xbA = (const uint4*)(xpack + ((size_t)(jA*C + c) << 4));
        uint4 loA = xbA[0], hiA = xbA[1];
        uint4 loB = make_uint4(0u,0u,0u,0u), hiB = make_uint4(0u,0u,0u,0u);
        int pC = p + 4;

        while (1) {
            bool hasC = pC < end;
            f32x4 gC0 = (f32x4)0.0f;
            u32x4 gC1 = (u32x4)0u;
            if (hasC) {
                const float* rC = edata + (size_t)pC * ED_STRIDE;
                gC0 = __builtin_nontemporal_load((const f32x4*)rC);
                gC1 = __builtin_nontemporal_load((const u32x4*)rC + 1);
            }
            if (hasB) {
                int jB = __float_as_int(gB0.w);
                const uint4* xbB = (const uint4*)(xpack + ((size_t)(jB*C + c) << 4));
                loB = xbB[0];
                hiB = xbB[1];
            }

            float fn[NCOMB];
            #pragma unroll
            for (int k = 0; k < NCOMB; ++k)
                fn[k] = FDOT2(gA1.w, Wh[k][3],
                        FDOT2(gA1.z, Wh[k][2],
                        FDOT2(gA1.y, Wh[k][1],
                        FDOT2(gA1.x, Wh[k][0], bc[k]))));

            float2 X0 = h2f(loA.x), X1 = h2f(loA.y), X2 = h2f(loA.z);
            float2 X3 = h2f(loA.w), X4 = h2f(hiA.x), X5 = h2f(hiA.y), X6 = h2f(hiA.z);
            float ux = gA0.x, uy = gA0.y, uz = gA0.z;
            float v0 = X0.x, v1x = X0.y, v1y = X1.x, v1z = X1.y;
            float c0 = X2.x, c1v = X2.y, c2 = X3.x, c3 = X3.y;
            float c4 = X4.x, c5 = X4.y, c6 = X5.x, c7 = X5.y, c8 = X6.x;

            float t2x = c0*ux + c1v*uy + c2*uz;
            float t2y = c3*ux + c4*uy + c5*uz;
            float t2z = c6*ux + c7*uy + c8*uz;
            float s1 = v1x*ux + v1y*uy + v1z*uz;
            float s2 = t2x*ux + t2y*uy + t2z*uz;

            acc[0] += fn[0]*v0 + fn[4]*s1 + fn[9]*s2;
            float al = fn[1]*v0 + fn[6]*s1;
            acc[1] += al*ux + fn[3]*v1x + fn[8]*t2x;
            acc[2] += al*uy + fn[3]*v1y + fn[8]*t2y;
            acc[3] += al*uz + fn[3]*v1z + fn[8]*t2z;
            float be = fn[2]*v0;
            float cax = be*ux + fn[5]*v1x + fn[10]*t2x;
            float cay = be*uy + fn[5]*v1y + fn[10]*t2y;
            float caz = be*uz + fn[5]*v1z + fn[10]*t2z;
            acc[4]  += cax*ux + fn[7]*c0;
            acc[5]  += cax*uy + fn[7]*c1v;
            acc[6]  += cax*uz + fn[7]*c2;
            acc[7]  += cay*ux + fn[7]*c3;
            acc[8]  += cay*uy + fn[7]*c4;
            acc[9]  += cay*uz + fn[7]*c5;
            acc[10] += caz*ux + fn[7]*c6;
            acc[11] += caz*uy + fn[7]*c7;
            acc[12] += caz*uz + fn[7]*c8;

            if (!hasB) break;
            gA0 = gB0; gA1 = gB1; loA = loB; hiA = hiB;
            gB0 = gC0; gB1 = gC1; hasB = hasC;
            pC += 2;
        }
    }

    #pragma unroll
    for (int q = 0; q < 13; ++q)
        acc[q] += __shfl_xor(acc[q], 32);

    if (h == 0) {
        float* out0 = out;
        float* out1 = out + N_ATOMS * C;
        float* out2 = out + N_ATOMS * C * 4;
        out0[a*C + c] = acc[0];
        #pragma unroll
        for (int m = 0; m < 3; ++m) out1[(a*C + c)*3 + m] = acc[1+m];
        #pragma unroll
        for (int q = 0; q < 9; ++q) out2[(a*C + c)*9 + q] = acc[4+q];
    }
}

// ============ FALLBACK tier2 (scan-based CSR, original x layouts) ===========
__global__ __launch_bounds__(256) void aux_kernel(
    const int* __restrict__ idx_i, int* __restrict__ counts)
{
    int t = blockIdx.x * blockDim.x + threadIdx.x;
    if (t < N_EDGES) atomicAdd(&counts[idx_i[t]], 1);
}

__global__ __launch_bounds__(1024) void scan_kernel(
    const int* __restrict__ counts, int* __restrict__ offsets,
    int* __restrict__ cursor)
{
    __shared__ int part[1024];
    const int PER = 10;
    int t = threadIdx.x;
    int base = t * PER;
    int s = 0;
    #pragma unroll
    for (int k = 0; k < PER; ++k) {
        int idx = base + k;
        s += (idx < N_ATOMS) ? counts[idx] : 0;
    }
    part[t] = s;
    __syncthreads();
    for (int off = 1; off < 1024; off <<= 1) {
        int v = (t >= off) ? part[t - off] : 0;
        __syncthreads();
        part[t] += v;
        __syncthreads();
    }
    int run = (t == 0) ? 0 : part[t - 1];
    #pragma unroll
    for (int k = 0; k < PER; ++k) {
        int idx = base + k;
        if (idx < N_ATOMS) { offsets[idx] = run; cursor[idx] = run; run += counts[idx]; }
    }
    if (t == 1023) offsets[N_ATOMS] = part[1023];
}

__global__ __launch_bounds__(256) void prep_scatter_kernel(
    const float* __restrict__ pos, const int* __restrict__ idx_i,
    const int* __restrict__ idx_j, int* __restrict__ cursor,
    float* __restrict__ edata)
{
    int e = blockIdx.x * blockDim.x + threadIdx.x;
    if (e >= N_EDGES) return;
    int i = idx_i[e], j = idx_j[e];
    float rx = pos[3*j+0] - pos[3*i+0];
    float ry = pos[3*j+1] - pos[3*i+1];
    float rz = pos[3*j+2] - pos[3*i+2];
    float d  = sqrtf(rx*rx + ry*ry + rz*rz + 1e-12f);
    float invd = 1.0f / d;
    float ux = rx*invd, uy = ry*invd, uz = rz*invd;
    const float PI = 3.14159265358979323846f;
    const float RC = 5.0f;
    float fc    = 0.5f * (cosf(PI * fminf(d, RC) / RC) + 1.0f);
    float pref  = sqrtf(2.0f / RC) * invd * fc;
    float phase = PI * d / RC;
    float s1, c1;
    sincosf(phase, &s1, &c1);
    float twoc = 2.0f * c1;
    float rbf[NB];
    float sp = 0.0f, sc = s1;
    #pragma unroll
    for (int nb = 0; nb < NB; ++nb) {
        rbf[nb] = pref * sc;
        float sn = twoc * sc - sp;
        sp = sc; sc = sn;
    }
    int slot = atomicAdd(&cursor[i], 1);
    float* rec = edata + (size_t)slot * ED_STRIDE;
    *(float4*)rec = make_float4(ux, uy, uz, __int_as_float(j));
    *((uint4*)rec + 1) = make_uint4(f2h(rbf[0], rbf[1]), f2h(rbf[2], rbf[3]),
                                    f2h(rbf[4], rbf[5]), f2h(rbf[6], rbf[7]));
}

__global__ __launch_bounds__(256, 2) void gather_fallback(
    const float* __restrict__ x0, const float* __restrict__ x1,
    const float* __restrict__ x2, const float* __restrict__ W,
    const float* __restrict__ b, const int* __restrict__ offsets,
    const float* __restrict__ edata, float* __restrict__ out)
{
    int wave = (blockIdx.x * blockDim.x + threadIdx.x) >> 6;
    int lane = threadIdx.x & 63;
    int c = lane & 31;
    int h = lane >> 5;
    if (wave >= N_ATOMS) return;
    int a = wave;

    float Wc[NCOMB][NB], bc[NCOMB];
    #pragma unroll
    for (int k = 0; k < NCOMB; ++k) {
        bc[k] = b[k*C + c] * (1.0f / 32.0f);
        #pragma unroll
        for (int nb = 0; nb < NB; ++nb)
            Wc[k][nb] = W[(k*NB + nb)*C + c] * (1.0f / 32.0f);
    }
    #pragma unroll
    for (int k = 0; k < NCOMB; ++k) {
        asm volatile("" : "+v"(bc[k]));
        #pragma unroll
        for (int nb = 0; nb < NB; ++nb) asm volatile("" : "+v"(Wc[k][nb]));
    }

    float acc[13];
    #pragma unroll
    for (int q = 0; q < 13; ++q) acc[q] = 0.0f;

    int start = offsets[a], end = offsets[a + 1];
    for (int p = start + h; p < end; p += 2) {
        const float* rec = edata + (size_t)p * ED_STRIDE;
        float4 g0 = *(const float4*)rec;
        uint4  g1 = *((const uint4*)rec + 1);
        float2 rp0 = h2f(g1.x), rp1 = h2f(g1.y), rp2 = h2f(g1.z), rp3 = h2f(g1.w);
        float ux = g0.x, uy = g0.y, uz = g0.z;
        float rbf[NB] = {rp0.x, rp0.y, rp1.x, rp1.y, rp2.x, rp2.y, rp3.x, rp3.y};
        int j = __float_as_int(g0.w);
        float fn[NCOMB];
        #pragma unroll
        for (int k = 0; k < NCOMB; ++k) {
            float t = bc[k];
            #pragma unroll
            for (int nb = 0; nb < NB; ++nb) t = fmaf(rbf[nb], Wc[k][nb], t);
            fn[k] = t;
        }
        float v0 = x0[j*C + c];
        float v1[3], v2[9];
        #pragma unroll
        for (int m = 0; m < 3; ++m) v1[m] = x1[(j*C + c)*3 + m];
        #pragma unroll
        for (int m = 0; m < 9; ++m) v2[m] = x2[(j*C + c)*9 + m];
        float u[3] = {ux, uy, uz};
        float t2[3];
        #pragma unroll
        for (int q = 0; q < 3; ++q)
            t2[q] = v2[q*3+0]*ux + v2[q*3+1]*uy + v2[q*3+2]*uz;
        float s1 = v1[0]*ux + v1[1]*uy + v1[2]*uz;
        float s2 = t2[0]*ux + t2[1]*uy + t2[2]*uz;
        acc[0] += fn[0]*v0 + fn[4]*s1 + fn[9]*s2;
        #pragma unroll
        for (int m = 0; m < 3; ++m)
            acc[1+m] += fn[1]*v0*u[m] + fn[3]*v1[m] + fn[6]*s1*u[m] + fn[8]*t2[m];
        #pragma unroll
        for (int q = 0; q < 3; ++q) {
            float ca = fn[2]*v0*u[q] + fn[5]*v1[q] + fn[10]*t2[q];
            #pragma unroll
            for (int bb = 0; bb < 3; ++bb)
                acc[4 + q*3 + bb] += ca*u[bb] + fn[7]*v2[q*3 + bb];
        }
    }

    #pragma unroll
    for (int q = 0; q < 13; ++q)
        acc[q] += __shfl_xor(acc[q], 32);

    if (h == 0) {
        float* out0 = out;
        float* out1 = out + N_ATOMS * C;
        float* out2 = out + N_ATOMS * C * 4;
        out0[a*C + c] = acc[0];
        #pragma unroll
        for (int m = 0; m < 3; ++m) out1[(a*C + c)*3 + m] = acc[1+m];
        #pragma unroll
        for (int q = 0; q < 9; ++q) out2[(a*C + c)*9 + q] = acc[4+q];
    }
}

__global__ __launch_bounds__(256) void edge_atomic_kernel(
    const float* __restrict__ x0, const float* __restrict__ x1,
    const float* __restrict__ x2, const float* __restrict__ pos,
    const float* __restrict__ W, const float* __restrict__ b,
    const int* __restrict__ idx_i, const int* __restrict__ idx_j,
    float* __restrict__ out)
{
    int tid = blockIdx.x * blockDim.x + threadIdx.x;
    int e = tid >> 5;
    int c = tid & 31;
    if (e >= N_EDGES) return;
    int i = idx_i[e], j = idx_j[e];
    float rx = pos[3*j+0] - pos[3*i+0];
    float ry = pos[3*j+1] - pos[3*i+1];
    float rz = pos[3*j+2] - pos[3*i+2];
    float d  = sqrtf(rx*rx + ry*ry + rz*rz + 1e-12f);
    float invd = 1.0f / d;
    float ux = rx*invd, uy = ry*invd, uz = rz*invd;
    const float PI = 3.14159265358979323846f;
    const float RC = 5.0f;
    float fc   = 0.5f * (cosf(PI * fminf(d, RC) / RC) + 1.0f);
    float pref = sqrtf(2.0f / RC) * invd * fc;
    float phase = PI * d / RC;
    float rbf[NB];
    #pragma unroll
    for (int nb = 0; nb < NB; ++nb) rbf[nb] = pref * sinf((float)(nb+1) * phase);
    float fn[NCOMB];
    #pragma unroll
    for (int k = 0; k < NCOMB; ++k) {
        float acc = b[k*C + c];
        #pragma unroll
        for (int nb = 0; nb < NB; ++nb) acc += rbf[nb] * W[(k*NB + nb)*C + c];
        fn[k] = acc * (1.0f / 32.0f);
    }
    float v0 = x0[j*C + c];
    float v1[3], v2[9];
    #pragma unroll
    for (int m = 0; m < 3; ++m) v1[m] = x1[(j*C + c)*3 + m];
    #pragma unroll
    for (int m = 0; m < 9; ++m) v2[m] = x2[(j*C + c)*9 + m];
    float u[3] = {ux, uy, uz};
    float t2[3];
    #pragma unroll
    for (int q = 0; q < 3; ++q)
        t2[q] = v2[q*3+0]*ux + v2[q*3+1]*uy + v2[q*3+2]*uz;
    float s1 = v1[0]*ux + v1[1]*uy + v1[2]*uz;
    float s2 = t2[0]*ux + t2[1]*uy + t2[2]*uz;
    float* out0 = out;
    float* out1 = out + N_ATOMS * C;
    float* out2 = out + N_ATOMS * C * 4;
    atomicAdd(&out0[i*C + c], fn[0]*v0 + fn[4]*s1 + fn[9]*s2);
    #pragma unroll
    for (int m = 0; m < 3; ++m)
        atomicAdd(&out1[(i*C + c)*3 + m],
                  fn[1]*v0*u[m] + fn[3]*v1[m] + fn[6]*s1*u[m] + fn[8]*t2[m]);
    #pragma unroll
    for (int q = 0; q < 3; ++q) {
        float ca = fn[2]*v0*u[q] + fn[5]*v1[q] + fn[10]*t2[q];
        #pragma unroll
        for (int bb = 0; bb < 3; ++bb)
            atomicAdd(&out2[(i*C + c)*9 + q*3 + bb], ca*u[bb] + fn[7]*v2[q*3 + bb]);
    }
}

extern "C" void kernel_launch(void* const* d_in, const int* in_sizes, int n_in,
                              void* d_out, int out_size, void* d_ws, size_t ws_size,
                              hipStream_t stream) {
    const float* x0    = (const float*)d_in[0];
    const float* x1    = (const float*)d_in[1];
    const float* x2    = (const float*)d_in[2];
    const float* pos   = (const float*)d_in[3];
    const float* W     = (const float*)d_in[4];
    const float* b     = (const float*)d_in[5];
    const int*   idx_i = (const int*)d_in[6];
    const int*   idx_j = (const int*)d_in[7];
    float* out = (float*)d_out;

    int eb = 256, eg = (N_EDGES + eb - 1) / eb;   // 1250, exact
    int ggrid = (N_ATOMS + 3) / 4;

    if (ws_size >= T0_NEED) {
        char* ws = (char*)d_ws;
        int*          cursor = (int*)(ws + T0_CURSOR);
        unsigned int* Wt     = (unsigned int*)(ws + T0_WT);
        float*        edata  = (float*)(ws + T0_EDATA);
        __half*       xpack  = (__half*)(ws + T0_XPACK);

        (void)hipMemsetAsync(cursor, 0, N_ATOMS * sizeof(int), stream);
        fused_prep_kernel<<<eg, eb, 0, stream>>>(x0, x1, x2, pos, idx_i, idx_j,
                                                 W, b, cursor, Wt, edata, xpack);
        gather_t0_kernel<<<ggrid, 256, 0, stream>>>(Wt, cursor, edata, xpack, out);
    } else if (ws_size >= WS_TIER2) {
        char* ws = (char*)d_ws;
        int*   counts  = (int*)(ws + WS_COUNTS);
        int*   offsets = (int*)(ws + WS_OFFSETS);
        int*   cursor  = (int*)(ws + WS_CURSOR);
        float* edata   = (float*)(ws + WS_EDATA);

        (void)hipMemsetAsync(counts, 0, N_ATOMS * sizeof(int), stream);
        aux_kernel<<<eg, eb, 0, stream>>>(idx_i, counts);
        scan_kernel<<<1, 1024, 0, stream>>>(counts, offsets, cursor);
        prep_scatter_kernel<<<eg, eb, 0, stream>>>(pos, idx_i, idx_j, cursor, edata);
        gather_fallback<<<ggrid, 256, 0, stream>>>(x0, x1, x2, W, b,
                                                   offsets, edata, out);
    } else {
        (void)hipMemsetAsync(d_out, 0, (size_t)out_size * sizeof(float), stream);
        int total_threads = N_EDGES * 32;
        int grid = (total_threads + 255) / 256;
        edge_atomic_kernel<<<grid, 256, 0, stream>>>(
            x0, x1, x2, pos, W, b, idx_i, idx_j, out);
    }
}